// Round 3
// baseline (75.193 us; speedup 1.0000x reference)
//
#include <hip/hip_runtime.h>

#define DIM 128
#define LEN 256
#define INV_SQRT_D 0.08838834764831845f

// ws layout (floats): Mt[128*128], c[128], w2[128], bqbk[1]
#define WS_MT   0
#define WS_C    (DIM * DIM)
#define WS_W2   (DIM * DIM + DIM)
#define WS_BQBK (DIM * DIM + 2 * DIM)

// ---- precompute: Mt[j][i] = sum_d Wk[i,d]*Wq[j,d]; c = Wk@bq; w2 = Wq@bk; bqbk ----
__global__ __launch_bounds__(128) void precompute_kernel(
    const float* __restrict__ Wq, const float* __restrict__ bq,
    const float* __restrict__ Wk, const float* __restrict__ bk,
    float* __restrict__ ws)
{
    const int t = threadIdx.x;
    const int j = blockIdx.x;
    if (j < DIM) {
        __shared__ float wqj[DIM];
        wqj[t] = Wq[j * DIM + t];
        __syncthreads();
        const float4* row = reinterpret_cast<const float4*>(Wk + t * DIM);
        float acc = 0.f;
        #pragma unroll 8
        for (int i = 0; i < DIM / 4; ++i) {
            float4 u = row[i];
            acc = fmaf(u.x, wqj[4*i+0], acc);
            acc = fmaf(u.y, wqj[4*i+1], acc);
            acc = fmaf(u.z, wqj[4*i+2], acc);
            acc = fmaf(u.w, wqj[4*i+3], acc);
        }
        ws[WS_MT + j * DIM + t] = acc;
    } else {
        __shared__ float bqs[DIM], bks[DIM], red[DIM];
        bqs[t] = bq[t]; bks[t] = bk[t];
        __syncthreads();
        const float4* rk = reinterpret_cast<const float4*>(Wk + t * DIM);
        const float4* rq = reinterpret_cast<const float4*>(Wq + t * DIM);
        float accC = 0.f, accW = 0.f;
        #pragma unroll 8
        for (int i = 0; i < DIM / 4; ++i) {
            float4 a  = rk[i];
            float4 b2 = rq[i];
            accC = fmaf(a.x,  bqs[4*i+0], accC);
            accC = fmaf(a.y,  bqs[4*i+1], accC);
            accC = fmaf(a.z,  bqs[4*i+2], accC);
            accC = fmaf(a.w,  bqs[4*i+3], accC);
            accW = fmaf(b2.x, bks[4*i+0], accW);
            accW = fmaf(b2.y, bks[4*i+1], accW);
            accW = fmaf(b2.z, bks[4*i+2], accW);
            accW = fmaf(b2.w, bks[4*i+3], accW);
        }
        ws[WS_C  + t] = accC;
        ws[WS_W2 + t] = accW;
        red[t] = bqs[t] * bks[t];
        __syncthreads();
        if (t == 0) {
            float s = 0.f;
            for (int i = 0; i < DIM; ++i) s += red[i];
            ws[WS_BQBK] = s;
        }
    }
}

// ---- main: one wave per batch, zero block barriers ----
__global__ __launch_bounds__(256) void fused_kernel(
    const float* __restrict__ sub_feat, const float* __restrict__ mask,
    const int* __restrict__ sub_index, const float* __restrict__ ws,
    float* __restrict__ out)
{
    const int t    = threadIdx.x;
    const int lane = t & 63;
    const int wv   = t >> 6;
    const int b    = blockIdx.x * 4 + wv;
    const int c32  = lane & 31;
    const int h    = lane >> 5;

    const float* Mt = ws + WS_MT;
    const float* cc = ws + WS_C;
    const float* w2 = ws + WS_W2;

    __shared__ int   idxs[4][LEN];
    __shared__ float g0s [4][DIM];
    __shared__ float vvs [4][DIM];
    __shared__ float scs [4][LEN];
    int*   idxw = idxs[wv];
    float* g0w  = g0s[wv];
    float* vw   = vvs[wv];
    float* scw  = scs[wv];

    // indices: 4 per lane, coalesced; also keep in registers
    const int* ib = sub_index + (size_t)b * LEN;
    const int i0 = ib[lane], i1 = ib[lane + 64], i2 = ib[lane + 128], i3 = ib[lane + 192];
    idxw[lane]       = i0;
    idxw[lane + 64]  = i1;
    idxw[lane + 128] = i2;
    idxw[lane + 192] = i3;

    // g0 = sub_feat[idx[0]], distributed float2 per lane + LDS copy for broadcast
    const int r0 = __shfl(i0, 0);
    const float2 g0p = reinterpret_cast<const float2*>(sub_feat + (size_t)r0 * DIM)[lane];
    g0w[2 * lane]     = g0p.x;
    g0w[2 * lane + 1] = g0p.y;

    // q0·bk = g0·w2 + bq·bk  (wave-wide shuffle reduce; all lanes end with sum)
    float qp = g0p.x * w2[2 * lane] + g0p.y * w2[2 * lane + 1];
    #pragma unroll
    for (int o = 32; o > 0; o >>= 1) qp += __shfl_xor(qp, o);
    const float q0bk = qp + ws[WS_BQBK];

    // v[i] = sum_j Mt[j][i]*g0[j] + c[i]; half h covers j in [64h,64h+64),
    // lane accumulates float4 for i = 4*c32..4*c32+3
    float4 vacc = make_float4(0.f, 0.f, 0.f, 0.f);
    {
        const int jb = h * 64;
        #pragma unroll 8
        for (int k = 0; k < 64; ++k) {
            const int j = jb + k;
            const float g = g0w[j];                       // LDS broadcast
            const float4 u = reinterpret_cast<const float4*>(Mt + j * DIM)[c32];
            vacc.x = fmaf(g, u.x, vacc.x);
            vacc.y = fmaf(g, u.y, vacc.y);
            vacc.z = fmaf(g, u.z, vacc.z);
            vacc.w = fmaf(g, u.w, vacc.w);
        }
    }
    vacc.x += __shfl_xor(vacc.x, 32);
    vacc.y += __shfl_xor(vacc.y, 32);
    vacc.z += __shfl_xor(vacc.z, 32);
    vacc.w += __shfl_xor(vacc.w, 32);
    if (h == 0) {
        const float4 cv = reinterpret_cast<const float4*>(cc)[c32];
        float4 vt;
        vt.x = vacc.x + cv.x;
        vt.y = vacc.y + cv.y;
        vt.z = vacc.z + cv.z;
        vt.w = vacc.w + cv.w;
        reinterpret_cast<float4*>(vw)[c32] = vt;          // wave-ordered LDS, no barrier
    }

    // scores: each lane owns 4 rows (j = lane, lane+64, lane+128, lane+192)
    const float4* p0 = reinterpret_cast<const float4*>(sub_feat + (size_t)i0 * DIM);
    const float4* p1 = reinterpret_cast<const float4*>(sub_feat + (size_t)i1 * DIM);
    const float4* p2 = reinterpret_cast<const float4*>(sub_feat + (size_t)i2 * DIM);
    const float4* p3 = reinterpret_cast<const float4*>(sub_feat + (size_t)i3 * DIM);
    float s0 = 0.f, s1 = 0.f, s2 = 0.f, s3 = 0.f;
    #pragma unroll 4
    for (int k = 0; k < DIM / 4; ++k) {
        const float4 vk = reinterpret_cast<const float4*>(vw)[k];   // broadcast
        const float4 u0 = p0[k];
        const float4 u1 = p1[k];
        const float4 u2 = p2[k];
        const float4 u3 = p3[k];
        s0 += u0.x * vk.x + u0.y * vk.y + u0.z * vk.z + u0.w * vk.w;
        s1 += u1.x * vk.x + u1.y * vk.y + u1.z * vk.z + u1.w * vk.w;
        s2 += u2.x * vk.x + u2.y * vk.y + u2.z * vk.z + u2.w * vk.w;
        s3 += u3.x * vk.x + u3.y * vk.y + u3.z * vk.z + u3.w * vk.w;
    }
    const float* mb = mask + (size_t)b * LEN;
    const float m0 = mb[lane], m1 = mb[lane + 64], m2 = mb[lane + 128], m3 = mb[lane + 192];
    s0 = (s0 + q0bk) * INV_SQRT_D + (1.f - m0) * (-10000.f);
    s1 = (s1 + q0bk) * INV_SQRT_D + (1.f - m1) * (-10000.f);
    s2 = (s2 + q0bk) * INV_SQRT_D + (1.f - m2) * (-10000.f);
    s3 = (s3 + q0bk) * INV_SQRT_D + (1.f - m3) * (-10000.f);

    // softmax over 256 = 4 locals × 64 lanes
    float pm = fmaxf(fmaxf(s0, s1), fmaxf(s2, s3));
    #pragma unroll
    for (int o = 32; o > 0; o >>= 1) pm = fmaxf(pm, __shfl_xor(pm, o));
    const float e0 = __expf(s0 - pm);
    const float e1 = __expf(s1 - pm);
    const float e2 = __expf(s2 - pm);
    const float e3 = __expf(s3 - pm);
    float ps = e0 + e1 + e2 + e3;
    #pragma unroll
    for (int o = 32; o > 0; o >>= 1) ps += __shfl_xor(ps, o);
    const float inv = 1.f / ps;
    scw[lane]       = e0 * inv;
    scw[lane + 64]  = e1 * inv;
    scw[lane + 128] = e2 * inv;
    scw[lane + 192] = e3 * inv;

    // weighted sum: lane owns d = 4*c32..+3; half h covers j = 2k+h
    float4 acc = make_float4(0.f, 0.f, 0.f, 0.f);
    #pragma unroll 8
    for (int k = 0; k < 128; ++k) {
        const int j = 2 * k + h;
        const int ij = idxw[j];                                   // LDS broadcast (2 addrs)
        const float p = scw[j];
        const float4 u = reinterpret_cast<const float4*>(sub_feat + (size_t)ij * DIM)[c32];
        acc.x = fmaf(p, u.x, acc.x);
        acc.y = fmaf(p, u.y, acc.y);
        acc.z = fmaf(p, u.z, acc.z);
        acc.w = fmaf(p, u.w, acc.w);
    }
    acc.x += __shfl_xor(acc.x, 32);
    acc.y += __shfl_xor(acc.y, 32);
    acc.z += __shfl_xor(acc.z, 32);
    acc.w += __shfl_xor(acc.w, 32);
    if (h == 0) {
        reinterpret_cast<float4*>(out + (size_t)b * DIM)[c32] = acc;
    }
}

extern "C" void kernel_launch(void* const* d_in, const int* in_sizes, int n_in,
                              void* d_out, int out_size, void* d_ws, size_t ws_size,
                              hipStream_t stream) {
    const float* sub_feat  = (const float*)d_in[0];
    const float* mask      = (const float*)d_in[1];
    const float* Wq        = (const float*)d_in[2];
    const float* bq        = (const float*)d_in[3];
    const float* Wk        = (const float*)d_in[4];
    const float* bk        = (const float*)d_in[5];
    const int*   sub_index = (const int*)d_in[6];
    float* outp = (float*)d_out;
    float* ws   = (float*)d_ws;

    const int B = in_sizes[6] / LEN;   // 2048

    precompute_kernel<<<dim3(DIM + 1), dim3(DIM), 0, stream>>>(Wq, bq, Wk, bk, ws);
    fused_kernel<<<dim3(B / 4), dim3(256), 0, stream>>>(sub_feat, mask, sub_index, ws, outp);
}

// Round 4
// 31.397 us; speedup vs baseline: 2.3949x; 2.3949x over previous
//
#include <hip/hip_runtime.h>

#define DIM 128
#define LEN 256
#define INV_SQRT_D 0.08838834764831845f

// ws layout (floats): Mt[128*128], c[128], w2[128], bqbk[1]
#define WS_MT   0
#define WS_C    (DIM * DIM)
#define WS_W2   (DIM * DIM + DIM)
#define WS_BQBK (DIM * DIM + 2 * DIM)

// ---- precompute: Mt[j][i] = sum_d Wk[i,d]*Wq[j,d]; c = Wk@bq; w2 = Wq@bk; bqbk ----
__global__ __launch_bounds__(128) void precompute_kernel(
    const float* __restrict__ Wq, const float* __restrict__ bq,
    const float* __restrict__ Wk, const float* __restrict__ bk,
    float* __restrict__ ws)
{
    const int t = threadIdx.x;
    const int j = blockIdx.x;
    if (j < DIM) {
        __shared__ float wqj[DIM];
        wqj[t] = Wq[j * DIM + t];
        __syncthreads();
        const float4* row = reinterpret_cast<const float4*>(Wk + t * DIM);
        float acc = 0.f;
        #pragma unroll 8
        for (int i = 0; i < DIM / 4; ++i) {
            float4 u = row[i];
            acc = fmaf(u.x, wqj[4*i+0], acc);
            acc = fmaf(u.y, wqj[4*i+1], acc);
            acc = fmaf(u.z, wqj[4*i+2], acc);
            acc = fmaf(u.w, wqj[4*i+3], acc);
        }
        ws[WS_MT + j * DIM + t] = acc;
    } else {
        __shared__ float bqs[DIM], bks[DIM], red[DIM];
        bqs[t] = bq[t]; bks[t] = bk[t];
        __syncthreads();
        const float4* rk = reinterpret_cast<const float4*>(Wk + t * DIM);
        const float4* rq = reinterpret_cast<const float4*>(Wq + t * DIM);
        float accC = 0.f, accW = 0.f;
        #pragma unroll 8
        for (int i = 0; i < DIM / 4; ++i) {
            float4 a  = rk[i];
            float4 b2 = rq[i];
            accC = fmaf(a.x,  bqs[4*i+0], accC);
            accC = fmaf(a.y,  bqs[4*i+1], accC);
            accC = fmaf(a.z,  bqs[4*i+2], accC);
            accC = fmaf(a.w,  bqs[4*i+3], accC);
            accW = fmaf(b2.x, bks[4*i+0], accW);
            accW = fmaf(b2.y, bks[4*i+1], accW);
            accW = fmaf(b2.z, bks[4*i+2], accW);
            accW = fmaf(b2.w, bks[4*i+3], accW);
        }
        ws[WS_C  + t] = accC;
        ws[WS_W2 + t] = accW;
        red[t] = bqs[t] * bks[t];
        __syncthreads();
        if (t == 0) {
            float s = 0.f;
            for (int i = 0; i < DIM; ++i) s += red[i];
            ws[WS_BQBK] = s;
        }
    }
}

// ---- main: 2 waves per batch (rows split 128/128), 16-lane-group coalesced rows,
//      single-pass online softmax, one barrier for the cross-wave merge ----
__global__ __launch_bounds__(256) void fused_kernel(
    const float* __restrict__ sub_feat, const float* __restrict__ mask,
    const int* __restrict__ sub_index, const float* __restrict__ ws,
    float* __restrict__ out)
{
    const int t    = threadIdx.x;
    const int lane = t & 63;
    const int wv   = t >> 6;           // 0..3
    const int pair = wv >> 1;          // batch slot in block
    const int rhalf= wv & 1;           // which 128 rows
    const int b    = blockIdx.x * 2 + pair;
    const int c32  = lane & 31;
    const int h    = lane >> 5;
    const int g    = lane >> 4;        // 16-lane group 0..3
    const int m16  = lane & 15;

    const float* Mt = ws + WS_MT;
    const float* cc = ws + WS_C;
    const float* w2 = ws + WS_W2;

    __shared__ float g0s [4][DIM];
    __shared__ int   idxs[4][DIM];
    __shared__ float bias[4][DIM];
    __shared__ float OW  [4][DIM];
    __shared__ float mzw [4][2];

    float* g0w = g0s[wv];
    int*   idw = idxs[wv];
    float* bw  = bias[wv];

    const int*   ib = sub_index + (size_t)b * LEN + rhalf * DIM;
    const float* mb = mask      + (size_t)b * LEN + rhalf * DIM;

    // stage this wave's 128 indices + mask-bias into LDS
    idw[lane]      = ib[lane];
    idw[lane + 64] = ib[lane + 64];
    bw[lane]       = (1.f - mb[lane])      * (-10000.f);
    bw[lane + 64]  = (1.f - mb[lane + 64]) * (-10000.f);

    // g0 row (batch's first gathered row)
    const int r0 = sub_index[(size_t)b * LEN];
    const float2 g0p = reinterpret_cast<const float2*>(sub_feat + (size_t)r0 * DIM)[lane];
    g0w[2 * lane]     = g0p.x;
    g0w[2 * lane + 1] = g0p.y;

    // q0·bk = g0·w2 + bq·bk
    float qp = g0p.x * w2[2 * lane] + g0p.y * w2[2 * lane + 1];
    #pragma unroll
    for (int o = 32; o > 0; o >>= 1) qp += __shfl_xor(qp, o);
    const float q0bk = qp + ws[WS_BQBK];

    // v[i] = sum_j Mt[j][i]*g0[j] + c[i]  (full matvec per wave; Mt is L1/L2-hot)
    float4 vacc = make_float4(0.f, 0.f, 0.f, 0.f);
    {
        const int jb = h * 64;
        #pragma unroll 8
        for (int k = 0; k < 64; ++k) {
            const int j = jb + k;
            const float gg = g0w[j];
            const float4 u = reinterpret_cast<const float4*>(Mt + j * DIM)[c32];
            vacc.x = fmaf(gg, u.x, vacc.x);
            vacc.y = fmaf(gg, u.y, vacc.y);
            vacc.z = fmaf(gg, u.z, vacc.z);
            vacc.w = fmaf(gg, u.w, vacc.w);
        }
    }
    vacc.x += __shfl_xor(vacc.x, 32);
    vacc.y += __shfl_xor(vacc.y, 32);
    vacc.z += __shfl_xor(vacc.z, 32);
    vacc.w += __shfl_xor(vacc.w, 32);
    const float4 cv = reinterpret_cast<const float4*>(cc)[c32];
    float4 vt;
    vt.x = vacc.x + cv.x; vt.y = vacc.y + cv.y;
    vt.z = vacc.z + cv.z; vt.w = vacc.w + cv.w;

    // distribute v into per-lane registers: vA = v[4*m16..+3], vB = v[64+4*m16..+3]
    float4 vA, vB;
    vA.x = __shfl(vt.x, m16);      vA.y = __shfl(vt.y, m16);
    vA.z = __shfl(vt.z, m16);      vA.w = __shfl(vt.w, m16);
    vB.x = __shfl(vt.x, m16 + 16); vB.y = __shfl(vt.y, m16 + 16);
    vB.z = __shfl(vt.z, m16 + 16); vB.w = __shfl(vt.w, m16 + 16);

    // single pass over this wave's 128 rows; group g handles row 4k+g
    float mx = -1e30f, Zr = 0.f;
    float O0=0.f,O1=0.f,O2=0.f,O3=0.f,O4=0.f,O5=0.f,O6=0.f,O7=0.f;
    #pragma unroll 4
    for (int k = 0; k < 32; ++k) {
        const int jl = 4 * k + g;
        const int ij = idw[jl];
        const float bj = bw[jl];
        const float* rp = sub_feat + (size_t)ij * DIM + 4 * m16;
        const float4 u0 = *reinterpret_cast<const float4*>(rp);
        const float4 u1 = *reinterpret_cast<const float4*>(rp + 64);
        float sd = u0.x*vA.x + u0.y*vA.y + u0.z*vA.z + u0.w*vA.w
                 + u1.x*vB.x + u1.y*vB.y + u1.z*vB.z + u1.w*vB.w;
        sd += __shfl_xor(sd, 1);
        sd += __shfl_xor(sd, 2);
        sd += __shfl_xor(sd, 4);
        sd += __shfl_xor(sd, 8);
        const float s  = (sd + q0bk) * INV_SQRT_D + bj;
        const float mn = fmaxf(mx, s);
        const float sc = __expf(mx - mn);
        const float e  = __expf(s - mn);
        Zr = Zr * sc + e;
        O0 = O0*sc + e*u0.x; O1 = O1*sc + e*u0.y;
        O2 = O2*sc + e*u0.z; O3 = O3*sc + e*u0.w;
        O4 = O4*sc + e*u1.x; O5 = O5*sc + e*u1.y;
        O6 = O6*sc + e*u1.z; O7 = O7*sc + e*u1.w;
        mx = mn;
    }

    // merge the 4 group-states within the wave (butterfly over lanes 16, 32)
    #pragma unroll
    for (int msk = 16; msk <= 32; msk <<= 1) {
        const float om = __shfl_xor(mx, msk);
        const float oZ = __shfl_xor(Zr, msk);
        const float M  = fmaxf(mx, om);
        const float a  = __expf(mx - M);
        const float bb = __expf(om - M);
        float p0 = __shfl_xor(O0, msk), p1 = __shfl_xor(O1, msk);
        float p2 = __shfl_xor(O2, msk), p3 = __shfl_xor(O3, msk);
        float p4 = __shfl_xor(O4, msk), p5 = __shfl_xor(O5, msk);
        float p6 = __shfl_xor(O6, msk), p7 = __shfl_xor(O7, msk);
        Zr = a*Zr + bb*oZ;
        O0 = a*O0 + bb*p0; O1 = a*O1 + bb*p1;
        O2 = a*O2 + bb*p2; O3 = a*O3 + bb*p3;
        O4 = a*O4 + bb*p4; O5 = a*O5 + bb*p5;
        O6 = a*O6 + bb*p6; O7 = a*O7 + bb*p7;
        mx = M;
    }

    // publish wave totals
    if (lane < 16) {
        reinterpret_cast<float4*>(&OW[wv][0])[m16]  = make_float4(O0, O1, O2, O3);
        reinterpret_cast<float4*>(&OW[wv][64])[m16] = make_float4(O4, O5, O6, O7);
    }
    if (lane == 0) { mzw[wv][0] = mx; mzw[wv][1] = Zr; }
    __syncthreads();

    // cross-wave merge + store: 256 threads = 2 batches x 128 dims
    {
        const int p = t >> 7;
        const int d = t & (DIM - 1);
        const float mA = mzw[2*p][0],   ZA = mzw[2*p][1];
        const float mB = mzw[2*p+1][0], ZB = mzw[2*p+1][1];
        const float M  = fmaxf(mA, mB);
        const float sA = __expf(mA - M);
        const float sB = __expf(mB - M);
        const float Zt = sA * ZA + sB * ZB;
        const float val = (sA * OW[2*p][d] + sB * OW[2*p+1][d]) / Zt;
        out[((size_t)blockIdx.x * 2 + p) * DIM + d] = val;
    }
}

extern "C" void kernel_launch(void* const* d_in, const int* in_sizes, int n_in,
                              void* d_out, int out_size, void* d_ws, size_t ws_size,
                              hipStream_t stream) {
    const float* sub_feat  = (const float*)d_in[0];
    const float* mask      = (const float*)d_in[1];
    const float* Wq        = (const float*)d_in[2];
    const float* bq        = (const float*)d_in[3];
    const float* Wk        = (const float*)d_in[4];
    const float* bk        = (const float*)d_in[5];
    const int*   sub_index = (const int*)d_in[6];
    float* outp = (float*)d_out;
    float* ws   = (float*)d_ws;

    const int B = in_sizes[6] / LEN;   // 2048

    precompute_kernel<<<dim3(DIM + 1), dim3(DIM), 0, stream>>>(Wq, bq, Wk, bk, ws);
    fused_kernel<<<dim3(B / 2), dim3(256), 0, stream>>>(sub_feat, mask, sub_index, ws, outp);
}